// Round 1
// baseline (353.334 us; speedup 1.0000x reference)
//
#include <hip/hip_runtime.h>
#include <stdint.h>

// ESN fused v4: wave-specialized pipeline.
//   waves 0-3: writeout(k-2) -> GEMM(k) -> stage(k+1) -> prefetch(k+2)
//   wave  4  : scan(k-1)   [lags one chunk; runs concurrent with GEMM]
// ONE barrier per chunk (was 2). pT/uB double-buffered.
// Scan chain shortened via exp2 folding: fma -> v_exp -> add -> rcp -> sub.
// B=32, D_IN=64, D_STATE=1024, L=2048, LEAK=0.5
#define B_   32
#define H_   64
#define P_   1024
#define L_   2048
#define TL   64
#define PB   64
#define NCH  (L_ / TL)
#define UST  68   // u32 row stride (272 B): b128 col reads conflict-free (17 f4/row)
#define PST  68   // f32 row stride

#define LOG2E     1.44269504088896340736f
#define TWO_LOG2E 2.88539008177792681472f

typedef __attribute__((ext_vector_type(8))) short short8;
typedef __attribute__((ext_vector_type(4))) float f32x4;
typedef __attribute__((ext_vector_type(4))) int   i32x4;

#if __has_builtin(__builtin_amdgcn_exp2f)
#define EXP2(x) __builtin_amdgcn_exp2f(x)
#else
#define EXP2(x) __expf(0.69314718055994530942f * (x))
#endif

__device__ __forceinline__ short8 as_short8(i32x4 v) {
    union { i32x4 i; short8 s; } u; u.i = v; return u.s;
}

// f = hi(bf16, trunc) + lo(bf16, RNE of remainder); packed as hi | lo<<16
__device__ __forceinline__ unsigned pack_hilo(float f) {
    unsigned ub = __float_as_uint(f);
    float    fh = __uint_as_float(ub & 0xFFFF0000u);
    float    rm = f - fh;                       // exact
    unsigned r  = __float_as_uint(rm);
    r += 0x7FFFu + ((r >> 16) & 1u);            // RNE to bf16
    return (ub >> 16) | (r & 0xFFFF0000u);
}

// 64 sequential recurrence steps on one p-row held in LDS (in-place),
// with next-group prefetch to hide LDS latency.
__device__ __forceinline__ void scan_row(float* row, float& x,
                                         const float d2l, const float bs2l) {
    float4 va = ((float4*)row)[0], vb = ((float4*)row)[1];
    #pragma unroll
    for (int g = 0; g < 8; ++g) {
        float4 na, nb;
        if (g < 7) { na = ((float4*)row)[2*g + 2]; nb = ((float4*)row)[2*g + 3]; }
        float v0[8] = {va.x, va.y, va.z, va.w, vb.x, vb.y, vb.z, vb.w};
        float xs[8];
        #pragma unroll
        for (int m = 0; m < 8; ++m) {
            // pre-scaled: z = 2*log2e*(u + x*d + bias); e = 2^z = exp(2*pre)
            const float sv = fmaf(TWO_LOG2E, v0[m], bs2l);        // independent
            const float e  = EXP2(fmaf(x, d2l, sv));              // chain: fma,exp
            x = fmaf(0.5f, x, 0.5f) - __builtin_amdgcn_rcpf(e + 1.0f); // add,rcp,sub
            xs[m] = x;
        }
        ((float4*)row)[2*g]     = make_float4(xs[0], xs[1], xs[2], xs[3]);
        ((float4*)row)[2*g + 1] = make_float4(xs[4], xs[5], xs[6], xs[7]);
        va = na; vb = nb;
    }
}

__global__ __launch_bounds__(320, 3)
void esn_fused(const float* __restrict__ u, const float* __restrict__ w_in,
               const float* __restrict__ w_hh, const float* __restrict__ bias,
               float* __restrict__ out) {
    __shared__ unsigned uB[2][TL * UST];   // [buf][l][h] packed hi/lo bf16   34.8 KB
    __shared__ float    pT[2][PB * PST];   // [buf][p][l]                     34.8 KB

    const int t   = threadIdx.x;
    const int bid = blockIdx.x;
    const int s_  = bid >> 3;                       // XCD swizzle: same-b on one XCD
    const int b   = ((s_ >> 4) << 3) | (bid & 7);
    const int p0  = (s_ & 15) * PB;

    const int wv  = t >> 6;        // wave 0..4
    const int ln  = t & 63;
    const int n16 = ln & 15;       // MFMA m/n index
    const int q   = ln >> 4;       // MFMA quad (k-group)

    const float* ub_ = u + (size_t)b * (H_ * L_);
    float* const ob0 = out + (size_t)b * (P_ * L_) + (size_t)p0 * L_;

    // ---- per-role persistent state ----
    short8 a_hi[2], a_lo[2];       // GEMM waves: w_in fragments (split bf16)
    float4 pf[4];                  // GEMM waves: staged u prefetch
    const int h = t >> 2, c = t & 3;   // staging map: 4 threads per u-row
    float x = 0.0f, d2l = 0.0f, bs2l = 0.0f;   // scan wave state

    if (t < 256) {
        // A-fragments: w_in rows, split bf16 hi/lo, held in registers
        const float* wrow = w_in + (size_t)(p0 + wv * 16 + n16) * H_;
        #pragma unroll
        for (int s = 0; s < 2; ++s) {
            float v[8];
            *(float4*)&v[0] = *(const float4*)(wrow + s * 32 + q * 8);
            *(float4*)&v[4] = *(const float4*)(wrow + s * 32 + q * 8 + 4);
            #pragma unroll
            for (int j = 0; j < 8; ++j) {
                unsigned ub = __float_as_uint(v[j]);
                a_hi[s][j] = (short)(ub >> 16);
                float rm = v[j] - __uint_as_float(ub & 0xFFFF0000u);
                unsigned r = __float_as_uint(rm);
                r += 0x7FFFu + ((r >> 16) & 1u);
                a_lo[s][j] = (short)(r >> 16);
            }
        }
        // prologue: stage chunk 0 into uB[0], then prefetch chunk 1
        const float* src = ub_ + (size_t)h * L_ + 4 * c;
        #pragma unroll
        for (int j = 0; j < 4; ++j) pf[j] = *(const float4*)(src + 16 * j);
        #pragma unroll
        for (int j = 0; j < 4; ++j) {
            const int l = 16 * j + 4 * c;
            uB[0][(l + 0) * UST + h] = pack_hilo(pf[j].x);
            uB[0][(l + 1) * UST + h] = pack_hilo(pf[j].y);
            uB[0][(l + 2) * UST + h] = pack_hilo(pf[j].z);
            uB[0][(l + 3) * UST + h] = pack_hilo(pf[j].w);
        }
        #pragma unroll
        for (int j = 0; j < 4; ++j) pf[j] = *(const float4*)(src + TL + 16 * j);
    } else {
        const int p = p0 + ln;
        d2l  = TWO_LOG2E * w_hh[(size_t)p * (P_ + 1)];   // 2*log2e*diag
        bs2l = TWO_LOG2E * bias[p];                      // 2*log2e*bias
    }
    __syncthreads();

    for (int k = 0; k < NCH; ++k) {
        const int kb = k & 1;
        if (t < 256) {
            // ---- writeout chunk k-2 from pT[kb] (scanned at iter k-1).
            //      Same buffer GEMM(k) writes below, but each wave reads ONLY
            //      its own 16 rows and writes ONLY those rows, and its DS reads
            //      precede its DS writes in program order -> no race. ----
            if (k >= 2) {
                const float* pbase = pT[kb];
                float* ob = ob0 + (size_t)(k - 2) * TL;
                const int rs = wv * 16 + (ln >> 2);
                #pragma unroll
                for (int jj = 0; jj < 4; ++jj) {
                    const int j = (ln & 3) + 4 * jj;
                    float4 o = *(const float4*)(pbase + rs * PST + 4 * j);
                    *(float4*)(ob + (size_t)rs * L_ + 4 * j) = o;
                }
            }
            // ---- GEMM chunk k: 64p x 64l, K=64, split bf16 (3 products) ----
            #pragma unroll
            for (int jt = 0; jt < 4; ++jt) {
                f32x4 acc = {0.0f, 0.0f, 0.0f, 0.0f};
                #pragma unroll
                for (int s = 0; s < 2; ++s) {
                    const unsigned* bp = &uB[kb][(jt * 16 + n16) * UST + s * 32 + q * 8];
                    i32x4 r0 = *(const i32x4*)bp;
                    i32x4 r1 = *(const i32x4*)(bp + 4);
                    i32x4 fh, fl;
                    fh.x = __builtin_amdgcn_perm(r0.y, r0.x, 0x05040100u);
                    fh.y = __builtin_amdgcn_perm(r0.w, r0.z, 0x05040100u);
                    fh.z = __builtin_amdgcn_perm(r1.y, r1.x, 0x05040100u);
                    fh.w = __builtin_amdgcn_perm(r1.w, r1.z, 0x05040100u);
                    fl.x = __builtin_amdgcn_perm(r0.y, r0.x, 0x07060302u);
                    fl.y = __builtin_amdgcn_perm(r0.w, r0.z, 0x07060302u);
                    fl.z = __builtin_amdgcn_perm(r1.y, r1.x, 0x07060302u);
                    fl.w = __builtin_amdgcn_perm(r1.w, r1.z, 0x07060302u);
                    short8 bh = as_short8(fh), bl = as_short8(fl);
                    acc = __builtin_amdgcn_mfma_f32_16x16x32_bf16(a_hi[s], bh, acc, 0, 0, 0);
                    acc = __builtin_amdgcn_mfma_f32_16x16x32_bf16(a_hi[s], bl, acc, 0, 0, 0);
                    acc = __builtin_amdgcn_mfma_f32_16x16x32_bf16(a_lo[s], bh, acc, 0, 0, 0);
                }
                // C/D: col(l)=lane&15, row(p)=quad*4+r -> b32 scatter into own strip
                #pragma unroll
                for (int r = 0; r < 4; ++r)
                    pT[kb][(wv * 16 + q * 4 + r) * PST + jt * 16 + n16] = acc[r];
            }
            // ---- stage chunk k+1 into uB[kb^1] (pf loaded last iteration) ----
            if (k + 1 < NCH) {
                #pragma unroll
                for (int j = 0; j < 4; ++j) {
                    const int l = 16 * j + 4 * c;
                    uB[kb ^ 1][(l + 0) * UST + h] = pack_hilo(pf[j].x);
                    uB[kb ^ 1][(l + 1) * UST + h] = pack_hilo(pf[j].y);
                    uB[kb ^ 1][(l + 2) * UST + h] = pack_hilo(pf[j].z);
                    uB[kb ^ 1][(l + 3) * UST + h] = pack_hilo(pf[j].w);
                }
            }
            // ---- prefetch chunk k+2 (consumed by stage at end of iter k+1:
            //      ~one full chunk of slack hides HBM/L2 latency) ----
            if (k + 2 < NCH) {
                const float* src = ub_ + (size_t)h * L_ + (size_t)(k + 2) * TL + 4 * c;
                #pragma unroll
                for (int j = 0; j < 4; ++j) pf[j] = *(const float4*)(src + 16 * j);
            }
        } else if (k >= 1) {
            // ---- scan chunk k-1 in pT[kb^1], concurrent with GEMM(k) ----
            scan_row(&pT[kb ^ 1][ln * PST], x, d2l, bs2l);
        }
        __syncthreads();   // single barrier per chunk
    }

    // ---- epilogue: drain the pipeline ----
    if (t < 256) {
        // writeout chunk NCH-2 (scanned during last loop iter)
        const float* pbase = pT[(NCH - 2) & 1];
        float* ob = ob0 + (size_t)(NCH - 2) * TL;
        const int rs = wv * 16 + (ln >> 2);
        #pragma unroll
        for (int jj = 0; jj < 4; ++jj) {
            const int j = (ln & 3) + 4 * jj;
            float4 o = *(const float4*)(pbase + rs * PST + 4 * j);
            *(float4*)(ob + (size_t)rs * L_ + 4 * j) = o;
        }
    } else {
        scan_row(&pT[(NCH - 1) & 1][ln * PST], x, d2l, bs2l);
    }
    __syncthreads();
    {   // final writeout: chunk NCH-1, all 5 waves
        const float* pbase = pT[(NCH - 1) & 1];
        float* ob = ob0 + (size_t)(NCH - 1) * TL;
        for (int i = t; i < PB * 16; i += 320) {
            const int p = i >> 4, j = i & 15;
            float4 o = *(const float4*)(pbase + p * PST + 4 * j);
            *(float4*)(ob + (size_t)p * L_ + 4 * j) = o;
        }
    }
}

extern "C" void kernel_launch(void* const* d_in, const int* in_sizes, int n_in,
                              void* d_out, int out_size, void* d_ws, size_t ws_size,
                              hipStream_t stream) {
    const float* u    = (const float*)d_in[0];  // [B, H, L]
    const float* w_in = (const float*)d_in[1];  // [P, H]
    const float* w_hh = (const float*)d_in[2];  // [P, P] (diag used)
    const float* bias = (const float*)d_in[3];  // [P]
    float* out = (float*)d_out;                 // [B, P, L]

    dim3 grid(B_ * (P_ / PB));  // 512 blocks
    dim3 block(320);            // 4 GEMM/stage waves + 1 scan wave
    esn_fused<<<grid, block, 0, stream>>>(u, w_in, w_hh, bias, out);
}

// Round 3
// 336.982 us; speedup vs baseline: 1.0485x; 1.0485x over previous
//
#include <hip/hip_runtime.h>
#include <stdint.h>

// ESN fused v5b: v3 skeleton (2-barrier, 4 waves) + scan-phase optimizations.
//   phase1: all 4 waves GEMM(k)          [pure GEMM, kept lean — v4 lesson]
//   phase2: wave0 scan(k)  ||  waves1-3 writeout(k-1) then stage(k+1)
// Scan: LDS group-prefetch + exp2 constant folding (chain: fma,exp,add,rcp,sub).
// v5b: resubmit of v5 (infra failure), EXP2 via __builtin_exp2f unconditionally.
// B=32, D_IN=64, D_STATE=1024, L=2048, LEAK=0.5
#define B_   32
#define H_   64
#define P_   1024
#define L_   2048
#define TL   64
#define PB   64
#define NCH  (L_ / TL)
#define UST  68   // uB row stride in u32 (row = 272 B, 16B-aligned, banks 4l+h)
#define PST  68   // pT row stride in f32

#define TWO_LOG2E 2.88539008177792681472f

typedef __attribute__((ext_vector_type(8))) short short8;
typedef __attribute__((ext_vector_type(4))) float f32x4;
typedef __attribute__((ext_vector_type(4))) int   i32x4;

// lowers to v_exp_f32 on gfx950 (hardware exp2)
#define EXP2(x) __builtin_exp2f(x)

__device__ __forceinline__ short8 as_short8(i32x4 v) {
    union { i32x4 i; short8 s; } u; u.i = v; return u.s;
}

// f = hi(bf16, trunc) + lo(bf16, RNE of remainder); packed as hi | lo<<16
__device__ __forceinline__ unsigned pack_hilo(float f) {
    unsigned ub = __float_as_uint(f);
    float    fh = __uint_as_float(ub & 0xFFFF0000u);
    float    rm = f - fh;                       // exact
    unsigned r  = __float_as_uint(rm);
    r += 0x7FFFu + ((r >> 16) & 1u);            // RNE to bf16
    return (ub >> 16) | (r & 0xFFFF0000u);
}

// 64 sequential recurrence steps on one p-row in LDS (in-place).
// Next-group prefetch hides ~120cy ds_read latency under the serial chain.
// Constants pre-scaled by 2*log2e so e = exp2(fma(...)) = exp(2*pre).
__device__ __forceinline__ void scan_row(float* row, float& x,
                                         const float d2l, const float bs2l) {
    float4 va = ((float4*)row)[0], vb = ((float4*)row)[1];
    #pragma unroll
    for (int g = 0; g < 8; ++g) {
        float4 na, nb;
        if (g < 7) { na = ((float4*)row)[2*g + 2]; nb = ((float4*)row)[2*g + 3]; }
        float v0[8] = {va.x, va.y, va.z, va.w, vb.x, vb.y, vb.z, vb.w};
        float xs[8];
        #pragma unroll
        for (int m = 0; m < 8; ++m) {
            const float sv = fmaf(TWO_LOG2E, v0[m], bs2l);            // off-chain
            const float e  = EXP2(fmaf(x, d2l, sv));                  // fma, exp
            x = fmaf(0.5f, x, 0.5f) - __builtin_amdgcn_rcpf(e + 1.0f);// add,rcp,sub
            xs[m] = x;
        }
        ((float4*)row)[2*g]     = make_float4(xs[0], xs[1], xs[2], xs[3]);
        ((float4*)row)[2*g + 1] = make_float4(xs[4], xs[5], xs[6], xs[7]);
        va = na; vb = nb;
    }
}

__global__ __launch_bounds__(256, 2)
void esn_fused(const float* __restrict__ u, const float* __restrict__ w_in,
               const float* __restrict__ w_hh, const float* __restrict__ bias,
               float* __restrict__ out) {
    __shared__ unsigned uB[TL * UST];      // [l][h] packed hi/lo bf16   17.4 KB
    __shared__ float    pT[2][PB * PST];   // [p][l]                     34.8 KB

    const int t   = threadIdx.x;
    const int bid = blockIdx.x;
    const int s_  = bid >> 3;                       // XCD swizzle: same-b on one XCD
    const int b   = ((s_ >> 4) << 3) | (bid & 7);
    const int p0  = (s_ & 15) * PB;

    const int wv  = t >> 6;        // wave 0..3 -> p-strip wv*16
    const int ln  = t & 63;
    const int n16 = ln & 15;       // MFMA m/n index
    const int q   = ln >> 4;       // MFMA quad (k-group)

    // ---- A-fragments: w_in rows, split bf16 hi/lo, held in registers ----
    short8 a_hi[2], a_lo[2];
    {
        const float* wrow = w_in + (size_t)(p0 + wv * 16 + n16) * H_;
        #pragma unroll
        for (int s = 0; s < 2; ++s) {
            float v[8];
            *(float4*)&v[0] = *(const float4*)(wrow + s * 32 + q * 8);
            *(float4*)&v[4] = *(const float4*)(wrow + s * 32 + q * 8 + 4);
            #pragma unroll
            for (int j = 0; j < 8; ++j) {
                unsigned ub = __float_as_uint(v[j]);
                a_hi[s][j] = (short)(ub >> 16);
                float rm = v[j] - __uint_as_float(ub & 0xFFFF0000u);
                unsigned r = __float_as_uint(rm);
                r += 0x7FFFu + ((r >> 16) & 1u);
                a_lo[s][j] = (short)(r >> 16);
            }
        }
    }

    // scan state (wave 0, one p per lane) — constants pre-scaled by 2*log2e
    float x = 0.0f, d2l = 0.0f, bs2l = 0.0f;
    if (t < PB) {
        d2l  = TWO_LOG2E * w_hh[(size_t)(p0 + t) * (P_ + 1)];
        bs2l = TWO_LOG2E * bias[p0 + t];
    }

    // staging maps (threads 64..255): jobA rows 16..63, jobB (t<128) rows 0..15
    const int  hA   = t >> 2;            // 16..63 for t>=64
    const int  cA   = t & 3;
    const bool jobB = (t >= 64 && t < 128);
    const int  hB   = (t - 64) >> 2;     // 0..15
    const float* ub_ = u + (size_t)b * (H_ * L_);

    float4 pfA[4], pfB[4];

    // ---- prologue: load + stage chunk 0 ----
    if (t >= 64) {
        #pragma unroll
        for (int j = 0; j < 4; ++j)
            pfA[j] = *(const float4*)(ub_ + (size_t)hA * L_ + 16 * j + 4 * cA);
        if (jobB)
            #pragma unroll
            for (int j = 0; j < 4; ++j)
                pfB[j] = *(const float4*)(ub_ + (size_t)hB * L_ + 16 * j + 4 * cA);
        #pragma unroll
        for (int j = 0; j < 4; ++j) {
            const int l = 16 * j + 4 * cA;
            uB[(l + 0) * UST + hA] = pack_hilo(pfA[j].x);
            uB[(l + 1) * UST + hA] = pack_hilo(pfA[j].y);
            uB[(l + 2) * UST + hA] = pack_hilo(pfA[j].z);
            uB[(l + 3) * UST + hA] = pack_hilo(pfA[j].w);
        }
        if (jobB)
            #pragma unroll
            for (int j = 0; j < 4; ++j) {
                const int l = 16 * j + 4 * cA;
                uB[(l + 0) * UST + hB] = pack_hilo(pfB[j].x);
                uB[(l + 1) * UST + hB] = pack_hilo(pfB[j].y);
                uB[(l + 2) * UST + hB] = pack_hilo(pfB[j].z);
                uB[(l + 3) * UST + hB] = pack_hilo(pfB[j].w);
            }
    }
    __syncthreads();

    for (int k = 0; k < NCH; ++k) {
        const int buf = k & 1;
        const int kn  = (k + 1 < NCH) ? k + 1 : k;

        // ---- prefetch next u chunk into registers (hides HBM under GEMM) ----
        if (t >= 64) {
            #pragma unroll
            for (int j = 0; j < 4; ++j)
                pfA[j] = *(const float4*)(ub_ + (size_t)hA * L_ + kn * TL + 16 * j + 4 * cA);
            if (jobB)
                #pragma unroll
                for (int j = 0; j < 4; ++j)
                    pfB[j] = *(const float4*)(ub_ + (size_t)hB * L_ + kn * TL + 16 * j + 4 * cA);
        }

        // ---- MFMA GEMM: 64p x 64l, K=64, split bf16 (3 products) ----
        #pragma unroll
        for (int jt = 0; jt < 4; ++jt) {
            f32x4 acc = {0.0f, 0.0f, 0.0f, 0.0f};
            #pragma unroll
            for (int s = 0; s < 2; ++s) {
                const unsigned* bp = &uB[(jt * 16 + n16) * UST + s * 32 + q * 8];
                i32x4 r0 = *(const i32x4*)bp;
                i32x4 r1 = *(const i32x4*)(bp + 4);
                i32x4 fh, fl;
                fh.x = __builtin_amdgcn_perm(r0.y, r0.x, 0x05040100u);
                fh.y = __builtin_amdgcn_perm(r0.w, r0.z, 0x05040100u);
                fh.z = __builtin_amdgcn_perm(r1.y, r1.x, 0x05040100u);
                fh.w = __builtin_amdgcn_perm(r1.w, r1.z, 0x05040100u);
                fl.x = __builtin_amdgcn_perm(r0.y, r0.x, 0x07060302u);
                fl.y = __builtin_amdgcn_perm(r0.w, r0.z, 0x07060302u);
                fl.z = __builtin_amdgcn_perm(r1.y, r1.x, 0x07060302u);
                fl.w = __builtin_amdgcn_perm(r1.w, r1.z, 0x07060302u);
                short8 bh = as_short8(fh), bl = as_short8(fl);
                acc = __builtin_amdgcn_mfma_f32_16x16x32_bf16(a_hi[s], bh, acc, 0, 0, 0);
                acc = __builtin_amdgcn_mfma_f32_16x16x32_bf16(a_hi[s], bl, acc, 0, 0, 0);
                acc = __builtin_amdgcn_mfma_f32_16x16x32_bf16(a_lo[s], bh, acc, 0, 0, 0);
            }
            // C/D: col(l) = lane&15, row(p) = quad*4 + r  -> scatter b32, 2-way max
            #pragma unroll
            for (int r = 0; r < 4; ++r)
                pT[buf][(wv * 16 + q * 4 + r) * PST + jt * 16 + n16] = acc[r];
        }
        __syncthreads();   // A: pT[buf] complete; uB reads done

        if (t < PB) {
            // ---- scan 64 steps in-place on own row (prefetched, exp2-folded) ----
            scan_row(&pT[buf][t * PST], x, d2l, bs2l);
        } else {
            // ---- write out chunk k-1 FIRST: stores drain under staging VALU ----
            if (k > 0) {
                const float* pbase = pT[1 - buf];
                float* ob = out + (size_t)b * (P_ * L_) + (size_t)p0 * L_ + (size_t)(k - 1) * TL;
                for (int i = t - 64; i < 1024; i += 192) {
                    const int p = i >> 4, j = i & 15;
                    float4 o = *(const float4*)(pbase + p * PST + 4 * j);
                    *(float4*)(ob + (size_t)p * L_ + 4 * j) = o;
                }
            }
            // ---- stage uB for chunk k+1 ----
            #pragma unroll
            for (int j = 0; j < 4; ++j) {
                const int l = 16 * j + 4 * cA;
                uB[(l + 0) * UST + hA] = pack_hilo(pfA[j].x);
                uB[(l + 1) * UST + hA] = pack_hilo(pfA[j].y);
                uB[(l + 2) * UST + hA] = pack_hilo(pfA[j].z);
                uB[(l + 3) * UST + hA] = pack_hilo(pfA[j].w);
            }
            if (jobB)
                #pragma unroll
                for (int j = 0; j < 4; ++j) {
                    const int l = 16 * j + 4 * cA;
                    uB[(l + 0) * UST + hB] = pack_hilo(pfB[j].x);
                    uB[(l + 1) * UST + hB] = pack_hilo(pfB[j].y);
                    uB[(l + 2) * UST + hB] = pack_hilo(pfB[j].z);
                    uB[(l + 3) * UST + hB] = pack_hilo(pfB[j].w);
                }
        }
        __syncthreads();   // B: scan + stage + writeout done
    }

    // ---- epilogue: write out last chunk (all 256 threads) ----
    {
        const int buf = (NCH - 1) & 1;
        const float* pbase = pT[buf];
        float* ob = out + (size_t)b * (P_ * L_) + (size_t)p0 * L_ + (size_t)(NCH - 1) * TL;
        for (int i = t; i < 1024; i += 256) {
            const int p = i >> 4, j = i & 15;
            float4 o = *(const float4*)(pbase + p * PST + 4 * j);
            *(float4*)(ob + (size_t)p * L_ + 4 * j) = o;
        }
    }
}

extern "C" void kernel_launch(void* const* d_in, const int* in_sizes, int n_in,
                              void* d_out, int out_size, void* d_ws, size_t ws_size,
                              hipStream_t stream) {
    const float* u    = (const float*)d_in[0];  // [B, H, L]
    const float* w_in = (const float*)d_in[1];  // [P, H]
    const float* w_hh = (const float*)d_in[2];  // [P, P] (diag used)
    const float* bias = (const float*)d_in[3];  // [P]
    float* out = (float*)d_out;                 // [B, P, L]

    dim3 grid(B_ * (P_ / PB));  // 512 blocks
    dim3 block(256);
    esn_fused<<<grid, block, 0, stream>>>(u, w_in, w_hh, bias, out);
}

// Round 4
// 334.545 us; speedup vs baseline: 1.0562x; 1.0073x over previous
//
#include <hip/hip_runtime.h>
#include <stdint.h>

// ESN fused v6: v3 skeleton + dedicated scan wave spanning both phases.
//   block = 320 threads = 5 waves, grid = 512, 2 blocks/CU.
//   waves 1-4 (t>=64): phase1 prefetch+GEMM(k)->pT[k&1]; phase2 stage(k+1)+writeout(k-1)
//   wave  0  (t<64)  : phase1 scan half2 of (k-1); phase2 scan half1 of (k)
// Scan spans barriers -> GEMM and scan overlap; workers keep v3's lean phases (v4 lesson).
// B=32, D_IN=64, D_STATE=1024, L=2048, LEAK=0.5
#define B_   32
#define H_   64
#define P_   1024
#define L_   2048
#define TL   64
#define PB   64
#define NCH  (L_ / TL)
#define UST  68   // uB row stride in u32 (row = 272 B, 16B-aligned)
#define PST  68   // pT row stride in f32

#define TWO_LOG2E 2.88539008177792681472f

typedef __attribute__((ext_vector_type(8))) short short8;
typedef __attribute__((ext_vector_type(4))) float f32x4;
typedef __attribute__((ext_vector_type(4))) int   i32x4;

// lowers to v_exp_f32 (hardware exp2)
#define EXP2(x) __builtin_exp2f(x)

__device__ __forceinline__ short8 as_short8(i32x4 v) {
    union { i32x4 i; short8 s; } u; u.i = v; return u.s;
}

// f = hi(bf16, trunc) + lo(bf16, RNE of remainder); packed as hi | lo<<16
__device__ __forceinline__ unsigned pack_hilo(float f) {
    unsigned ub = __float_as_uint(f);
    float    fh = __uint_as_float(ub & 0xFFFF0000u);
    float    rm = f - fh;                       // exact
    unsigned r  = __float_as_uint(rm);
    r += 0x7FFFu + ((r >> 16) & 1u);            // RNE to bf16
    return (ub >> 16) | (r & 0xFFFF0000u);
}

// 32 sequential recurrence steps (4 groups of 8) on one p-row in LDS, in-place.
// Constants pre-scaled by 2*log2e: e = exp2(fma(...)) = exp(2*pre).
// Next-group prefetch hides ds_read latency under the serial chain.
template<int G0>
__device__ __forceinline__ void scan_half(float* row, float& x,
                                          const float d2l, const float bs2l) {
    float4 va = ((float4*)row)[2 * G0], vb = ((float4*)row)[2 * G0 + 1];
    #pragma unroll
    for (int gg = 0; gg < 4; ++gg) {
        const int g = G0 + gg;
        float4 na, nb;
        if (gg < 3) { na = ((float4*)row)[2*g + 2]; nb = ((float4*)row)[2*g + 3]; }
        float v0[8] = {va.x, va.y, va.z, va.w, vb.x, vb.y, vb.z, vb.w};
        float xs[8];
        #pragma unroll
        for (int m = 0; m < 8; ++m) {
            const float sv = fmaf(TWO_LOG2E, v0[m], bs2l);            // off-chain
            const float e  = EXP2(fmaf(x, d2l, sv));                  // fma, exp
            x = fmaf(0.5f, x, 0.5f) - __builtin_amdgcn_rcpf(e + 1.0f);// add,rcp,sub
            xs[m] = x;
        }
        ((float4*)row)[2*g]     = make_float4(xs[0], xs[1], xs[2], xs[3]);
        ((float4*)row)[2*g + 1] = make_float4(xs[4], xs[5], xs[6], xs[7]);
        va = na; vb = nb;
    }
}

__global__ __launch_bounds__(320, 3)
void esn_fused(const float* __restrict__ u, const float* __restrict__ w_in,
               const float* __restrict__ w_hh, const float* __restrict__ bias,
               float* __restrict__ out) {
    __shared__ unsigned uB[TL * UST];      // [l][h] packed hi/lo bf16   17.4 KB
    __shared__ float    pT[2][PB * PST];   // [p][l]                     34.8 KB

    const int t   = threadIdx.x;
    const int bid = blockIdx.x;
    const int s_  = bid >> 3;                       // XCD swizzle: same-b on one XCD
    const int b   = ((s_ >> 4) << 3) | (bid & 7);
    const int p0  = (s_ & 15) * PB;

    const int wv  = t >> 6;        // wave 0 = scan; waves 1..4 = GEMM strip (wv-1)
    const int ln  = t & 63;
    const int n16 = ln & 15;       // MFMA m/n index
    const int q   = ln >> 4;       // MFMA quad (k-group)

    const float* ub_ = u + (size_t)b * (H_ * L_);
    float* const ob0 = out + (size_t)b * (P_ * L_) + (size_t)p0 * L_;

    // ---- per-role persistent state ----
    short8 a_hi[2], a_lo[2];           // workers: w_in fragments (split bf16)
    float4 pf[4];                      // workers: u prefetch regs
    const int h = (t - 64) >> 2;       // staging: 256 workers = 64 rows x 4 quarters
    const int c = (t - 64) & 3;
    float x = 0.0f, d2l = 0.0f, bs2l = 0.0f;   // scan wave state

    if (t >= 64) {
        // A-fragments: w_in rows for strip wv-1, split bf16 hi/lo, in registers
        const float* wrow = w_in + (size_t)(p0 + (wv - 1) * 16 + n16) * H_;
        #pragma unroll
        for (int s = 0; s < 2; ++s) {
            float v[8];
            *(float4*)&v[0] = *(const float4*)(wrow + s * 32 + q * 8);
            *(float4*)&v[4] = *(const float4*)(wrow + s * 32 + q * 8 + 4);
            #pragma unroll
            for (int j = 0; j < 8; ++j) {
                unsigned ub = __float_as_uint(v[j]);
                a_hi[s][j] = (short)(ub >> 16);
                float rm = v[j] - __uint_as_float(ub & 0xFFFF0000u);
                unsigned r = __float_as_uint(rm);
                r += 0x7FFFu + ((r >> 16) & 1u);
                a_lo[s][j] = (short)(r >> 16);
            }
        }
        // prologue: load + stage chunk 0 (each worker: 1 row-quarter, even split)
        const float* src = ub_ + (size_t)h * L_ + 4 * c;
        #pragma unroll
        for (int j = 0; j < 4; ++j) pf[j] = *(const float4*)(src + 16 * j);
        #pragma unroll
        for (int j = 0; j < 4; ++j) {
            const int l = 16 * j + 4 * c;
            uB[(l + 0) * UST + h] = pack_hilo(pf[j].x);
            uB[(l + 1) * UST + h] = pack_hilo(pf[j].y);
            uB[(l + 2) * UST + h] = pack_hilo(pf[j].z);
            uB[(l + 3) * UST + h] = pack_hilo(pf[j].w);
        }
    } else {
        // scan constants pre-scaled by 2*log2e
        d2l  = TWO_LOG2E * w_hh[(size_t)(p0 + ln) * (P_ + 1)];
        bs2l = TWO_LOG2E * bias[p0 + ln];
    }
    __syncthreads();

    for (int k = 0; k < NCH; ++k) {
        const int buf = k & 1;
        if (t >= 64) {
            // ---- phase1: prefetch u(k+1) into regs, GEMM(k) -> pT[buf] ----
            const int kn = (k + 1 < NCH) ? k + 1 : k;
            const float* src = ub_ + (size_t)h * L_ + (size_t)kn * TL + 4 * c;
            #pragma unroll
            for (int j = 0; j < 4; ++j) pf[j] = *(const float4*)(src + 16 * j);

            #pragma unroll
            for (int jt = 0; jt < 4; ++jt) {
                f32x4 acc = {0.0f, 0.0f, 0.0f, 0.0f};
                #pragma unroll
                for (int s = 0; s < 2; ++s) {
                    const unsigned* bp = &uB[(jt * 16 + n16) * UST + s * 32 + q * 8];
                    i32x4 r0 = *(const i32x4*)bp;
                    i32x4 r1 = *(const i32x4*)(bp + 4);
                    i32x4 fh, fl;
                    fh.x = __builtin_amdgcn_perm(r0.y, r0.x, 0x05040100u);
                    fh.y = __builtin_amdgcn_perm(r0.w, r0.z, 0x05040100u);
                    fh.z = __builtin_amdgcn_perm(r1.y, r1.x, 0x05040100u);
                    fh.w = __builtin_amdgcn_perm(r1.w, r1.z, 0x05040100u);
                    fl.x = __builtin_amdgcn_perm(r0.y, r0.x, 0x07060302u);
                    fl.y = __builtin_amdgcn_perm(r0.w, r0.z, 0x07060302u);
                    fl.z = __builtin_amdgcn_perm(r1.y, r1.x, 0x07060302u);
                    fl.w = __builtin_amdgcn_perm(r1.w, r1.z, 0x07060302u);
                    short8 bh = as_short8(fh), bl = as_short8(fl);
                    acc = __builtin_amdgcn_mfma_f32_16x16x32_bf16(a_hi[s], bh, acc, 0, 0, 0);
                    acc = __builtin_amdgcn_mfma_f32_16x16x32_bf16(a_hi[s], bl, acc, 0, 0, 0);
                    acc = __builtin_amdgcn_mfma_f32_16x16x32_bf16(a_lo[s], bh, acc, 0, 0, 0);
                }
                // C/D: col(l)=lane&15, row(p)=quad*4+r -> b32 scatter into own strip
                #pragma unroll
                for (int r = 0; r < 4; ++r)
                    pT[buf][((wv - 1) * 16 + q * 4 + r) * PST + jt * 16 + n16] = acc[r];
            }
        } else if (k > 0) {
            // ---- phase1: scan half2 of chunk k-1 (pT[1-buf], disjoint from GEMM) ----
            __builtin_amdgcn_s_setprio(1);
            scan_half<4>(&pT[1 - buf][ln * PST], x, d2l, bs2l);
            __builtin_amdgcn_s_setprio(0);
        }
        __syncthreads();   // A: pT[buf] complete; scan(k-1) complete; uB reads done

        if (t >= 64) {
            // ---- phase2: stage uB for chunk k+1 (v3-proven order), then
            //      writeout chunk k-1 (scan finished at barrier A) ----
            if (k + 1 < NCH) {
                #pragma unroll
                for (int j = 0; j < 4; ++j) {
                    const int l = 16 * j + 4 * c;
                    uB[(l + 0) * UST + h] = pack_hilo(pf[j].x);
                    uB[(l + 1) * UST + h] = pack_hilo(pf[j].y);
                    uB[(l + 2) * UST + h] = pack_hilo(pf[j].z);
                    uB[(l + 3) * UST + h] = pack_hilo(pf[j].w);
                }
            }
            if (k > 0) {
                const float* pbase = pT[1 - buf];
                float* ob = ob0 + (size_t)(k - 1) * TL;
                #pragma unroll
                for (int i = t - 64; i < 1024; i += 256) {
                    const int p = i >> 4, j = i & 15;
                    float4 o = *(const float4*)(pbase + p * PST + 4 * j);
                    *(float4*)(ob + (size_t)p * L_ + 4 * j) = o;
                }
            }
        } else {
            // ---- phase2: scan half1 of chunk k (pT[buf]) ----
            __builtin_amdgcn_s_setprio(1);
            scan_half<0>(&pT[buf][ln * PST], x, d2l, bs2l);
            __builtin_amdgcn_s_setprio(0);
        }
        __syncthreads();   // B: stage + writeout + scan-half done
    }

    // ---- epilogue: finish scan of last chunk, then write it out ----
    if (t < 64) {
        __builtin_amdgcn_s_setprio(1);
        scan_half<4>(&pT[(NCH - 1) & 1][ln * PST], x, d2l, bs2l);
        __builtin_amdgcn_s_setprio(0);
    }
    __syncthreads();
    {
        const float* pbase = pT[(NCH - 1) & 1];
        float* ob = ob0 + (size_t)(NCH - 1) * TL;
        for (int i = t; i < 1024; i += 320) {
            const int p = i >> 4, j = i & 15;
            float4 o = *(const float4*)(pbase + p * PST + 4 * j);
            *(float4*)(ob + (size_t)p * L_ + 4 * j) = o;
        }
    }
}

extern "C" void kernel_launch(void* const* d_in, const int* in_sizes, int n_in,
                              void* d_out, int out_size, void* d_ws, size_t ws_size,
                              hipStream_t stream) {
    const float* u    = (const float*)d_in[0];  // [B, H, L]
    const float* w_in = (const float*)d_in[1];  // [P, H]
    const float* w_hh = (const float*)d_in[2];  // [P, P] (diag used)
    const float* bias = (const float*)d_in[3];  // [P]
    float* out = (float*)d_out;                 // [B, P, L]

    dim3 grid(B_ * (P_ / PB));  // 512 blocks
    dim3 block(320);            // 4 GEMM/stage waves + 1 scan wave
    esn_fused<<<grid, block, 0, stream>>>(u, w_in, w_hh, bias, out);
}